// Round 5
// baseline (2660.812 us; speedup 1.0000x reference)
//
#include <hip/hip_runtime.h>
#include <cstdint>
#include <cstddef>

typedef __attribute__((ext_vector_type(8)))  short short8;   // 8 bf16 (4 VGPRs)
typedef __attribute__((ext_vector_type(4)))  float f32x4;
typedef __attribute__((ext_vector_type(16))) float f32x16;

#define HH     100
#define G4     400
#define NCOL   416          // 400 gates + 5 logits + 11 pad = 13 tiles of 32
#define NTILE  13
#define KP     128          // K padded to 128 (k>=100 zero)
#define KT8    8            // 8 k-tiles of 16
#define BTOT   8192
#define TST    512
#define ROWS   32
#define NBLK   256
#define BLOCK  832          // 13 waves; wave w owns column tile w
#define ZSTR   36           // z_lds row stride (words): conflict-free (proven)
#define AST    136          // h_hi/h_lo row stride (halfwords); 16B-aligned
#define TANHC  1.5f
#define EPSF   1e-9f

__device__ unsigned short d_Bhi[NTILE*KT8*64*8];  // [W_h|W_ops|0] hi, B-frag order
__device__ unsigned short d_Blo[NTILE*KT8*64*8];  // lo residual
__device__ float d_Ep2[6*G4];                     // emb @ W_x  [e][je][g]
__device__ float d_Z0t[(size_t)G4*BTOT];          // (x0 @ W_x)^T [n][b]

static __device__ __forceinline__ unsigned short bf16hi(float f){
  unsigned u = __float_as_uint(f);
  return (unsigned short)((u + 0x7FFFu + ((u>>16)&1u)) >> 16);   // RNE
}
static __device__ __forceinline__ float bf16f(unsigned short s){
  return __uint_as_float(((unsigned)s)<<16);
}
static __device__ __forceinline__ float frcp(float x){ return __builtin_amdgcn_rcpf(x); }
static __device__ __forceinline__ float sigf(float x){ return frcp(1.0f + __expf(-x)); }
static __device__ __forceinline__ float tanh_f(float x){ return 1.0f - 2.0f*frcp(__expf(2.0f*x) + 1.0f); }

// ---- setup kernels -------------------------------------------------------

// pack [W_h | W_ops | 0] (K zero-padded to 128) into 32x32x16 B fragments,
// split to bf16 hi + lo.  B[k][n]: n = tile*32 + (lane&31), k = kt*16 + (lane>>5)*8 + i
__global__ void setup_bpack(const float* __restrict__ Wh, const float* __restrict__ Wops){
  int idx = blockIdx.x*blockDim.x + threadIdx.x;     // NTILE*KT8*64 = 6656
  if (idx >= NTILE*KT8*64) return;
  int tile = idx/(KT8*64), rem = idx - tile*(KT8*64), kt = rem>>6, ln = rem&63;
  int n  = tile*32 + (ln & 31);
  int kb = kt*16 + (ln>>5)*8;
  #pragma unroll
  for (int i = 0; i < 8; ++i){
    int k = kb + i;
    float w = 0.f;
    if (k < HH){
      if (n < G4)           w = Wh[k*G4 + n];
      else if (n < G4 + 5)  w = Wops[k*5 + (n - G4)];
    }
    unsigned short hi = bf16hi(w);
    unsigned short lo = bf16hi(w - bf16f(hi));
    d_Bhi[idx*8+i] = hi;
    d_Blo[idx*8+i] = lo;
  }
}

__global__ void setup_emb(const float* __restrict__ emb, const float* __restrict__ Wx){
  int idx = blockIdx.x*blockDim.x + threadIdx.x;     // 2400
  if (idx >= 6*G4) return;
  int e = idx/G4, r2 = idx - e*G4, je = r2>>2, g = r2&3;   // [e][je][g]
  float s = 0.f;
  for (int k = 0; k < HH; ++k) s = fmaf(emb[e*HH+k], Wx[k*G4 + g*HH + je], s);
  d_Ep2[idx] = s;
}

// LDS-staged coalesced Z0 = x0 @ W_x, stored transposed [n][b]
__global__ __launch_bounds__(256) void setup_z0(const float* __restrict__ x0,
                                                const float* __restrict__ Wx){
  __shared__ float xs[64*101];
  const int bb = blockIdx.x * 64;                    // 128 blocks
  for (int i = threadIdx.x; i < 64*HH; i += 256){
    int r = i/HH, k = i - r*HH;
    xs[r*101 + k] = x0[(size_t)(bb + r)*HH + k];
  }
  __syncthreads();
  const int bl = threadIdx.x & 63;
  for (int ng = threadIdx.x >> 6; ng < HH; ng += 4){
    f32x4 a = {0.f,0.f,0.f,0.f};
    for (int k = 0; k < HH; ++k){
      f32x4 w = *(const f32x4*)&Wx[k*G4 + ng*4];
      a += w * xs[bl*101 + k];
    }
    #pragma unroll
    for (int q = 0; q < 4; ++q)
      d_Z0t[(size_t)(ng*4+q)*BTOT + bb + bl] = a[q];
  }
}

// ---- main persistent kernel ---------------------------------------------

__global__ __launch_bounds__(BLOCK, 4) void rnn_main(
    const float* __restrict__ u, float* __restrict__ out)
{
  __shared__ __align__(16) float z_lds[NCOL*ZSTR];          // 59904 B [col][row]
  __shared__ __align__(16) unsigned short h_hi[ROWS*AST];   //  8704 B (swizzled)
  __shared__ __align__(16) unsigned short h_lo[ROWS*AST];   //  8704 B
  __shared__ __align__(16) float Ep2_l[6*G4];               //  9600 B [e][je][g]
  __shared__ __align__(16) float samp[5*33];                //   660 B
  __shared__ __align__(16) float gn_lds[ROWS*5];            //   640 B
  __shared__ int op_lds[ROWS];

  const int tid  = threadIdx.x;
  const int wave = tid >> 6;          // wave w owns column tile w
  const int lane = tid & 63;
  const int m    = lane & 31;         // MFMA row (A) / col-in-tile (B,C)
  const int hh   = lane >> 5;
  const int row0 = blockIdx.x * ROWS;

  // prologue: zero h frags (incl. K-pad), stage Ep2, load B frags to VGPRs
  for (int i = tid; i < ROWS*AST/2; i += BLOCK){
    ((unsigned*)h_hi)[i] = 0u;
    ((unsigned*)h_lo)[i] = 0u;
  }
  for (int i = tid; i < 6*G4; i += BLOCK) Ep2_l[i] = d_Ep2[i];

  short8 bh[KT8], bl[KT8];
  {
    const short8* bph = (const short8*)d_Bhi;
    const short8* bpl = (const short8*)d_Blo;
    #pragma unroll
    for (int kt = 0; kt < KT8; ++kt){
      int fi = (wave*KT8 + kt)*64 + lane;
      bh[kt] = bph[fi];
      bl[kt] = bpl[fi];
    }
  }

  float c_st[4] = {0.f,0.f,0.f,0.f};
  float lp_acc = 0.f, ent_acc = 0.f;

  for (int t = 0; t <= TST; ++t){
    if (t == 0){
      // z_0 gates = x0 @ W_x (precomputed); logits cols unused at t=0
      for (int i = tid; i < G4*ROWS; i += BLOCK){
        int n = i >> 5, r = i & 31;
        z_lds[n*ZSTR + r] = d_Z0t[(size_t)n*BTOT + row0 + r];
      }
    } else {
      // ---- G: 32x32 MFMA, 4-product split-bf16, K=128 ----
      f32x16 acc;
      #pragma unroll
      for (int i = 0; i < 16; ++i) acc[i] = 0.f;
      #pragma unroll
      for (int kt = 0; kt < KT8; ++kt){
        const int grp = ((kt*2 + hh) + (m >> 2)) & 15;    // rotation swizzle
        const int ofs = m*AST + grp*8;
        short8 ah = *(const short8*)&h_hi[ofs];
        short8 al = *(const short8*)&h_lo[ofs];
        acc = __builtin_amdgcn_mfma_f32_32x32x16_bf16(ah, bh[kt], acc, 0,0,0);
        acc = __builtin_amdgcn_mfma_f32_32x32x16_bf16(al, bh[kt], acc, 0,0,0);
        acc = __builtin_amdgcn_mfma_f32_32x32x16_bf16(ah, bl[kt], acc, 0,0,0);
        acc = __builtin_amdgcn_mfma_f32_32x32x16_bf16(al, bl[kt], acc, 0,0,0);
      }
      // z-store: C/D row=(reg&3)+8*(reg>>2)+4*(lane>>5), col=lane&31 (conflict-free)
      const int col = wave*32 + m;
      #pragma unroll
      for (int p = 0; p < 4; ++p){
        f32x4 v = {acc[p*4+0], acc[p*4+1], acc[p*4+2], acc[p*4+3]};
        *(f32x4*)&z_lds[col*ZSTR + 8*p + 4*hh] = v;
      }
      // ---- sampling for step t-1 (wave 12 owns logit cols 400..404) ----
      if (wave == 12){
        if (m >= 16 && m < 21){
          int o = m - 16;
          #pragma unroll
          for (int p = 0; p < 4; ++p)
            #pragma unroll
            for (int q = 0; q < 4; ++q)
              samp[o*33 + 8*p + 4*hh + q] = acc[p*4+q];
        }
        // same-wave LDS dep: compiler inserts lgkmcnt wait before reads
        if (lane < 32){
          int r = lane;
          float l[5];
          #pragma unroll
          for (int o = 0; o < 5; ++o) l[o] = TANHC * tanh_f(samp[o*33 + r]);
          int op = 0; float best = -1e30f;
          #pragma unroll
          for (int o = 0; o < 5; ++o){
            float v = l[o] + gn_lds[r*5 + o];
            if (v > best){ best = v; op = o; }           // strict >: first-max ties
          }
          float mx = fmaxf(fmaxf(fmaxf(l[0],l[1]), fmaxf(l[2],l[3])), l[4]);
          float se = 0.f;
          #pragma unroll
          for (int o = 0; o < 5; ++o) se += __expf(l[o] - mx);
          float lse = mx + __logf(se);
          float cur = lse - l[op];
          lp_acc  += cur;
          ent_acc += cur * __expf(-cur);
          op_lds[r] = op;
          out[2*BTOT + (size_t)(t-1)*BTOT + row0 + r] = (float)op;
        }
      }
    }
    if (t == TST) break;          // final iteration: logits_511 only
    __syncthreads();   // b1: z + op_{t-1} ready

    // ---- E: LSTM elementwise + bf16 hi/lo split write ----
    if (tid < 800){
      const int je = tid >> 3, rg = tid & 7, r4e = rg*4;
      f32x4 z0 = *(const f32x4*)&z_lds[( 0 + je)*ZSTR + r4e];
      f32x4 z1 = *(const f32x4*)&z_lds[(100 + je)*ZSTR + r4e];
      f32x4 z2 = *(const f32x4*)&z_lds[(200 + je)*ZSTR + r4e];
      f32x4 z3 = *(const f32x4*)&z_lds[(300 + je)*ZSTR + r4e];
      if (t > 0){
        #pragma unroll
        for (int rr = 0; rr < 4; ++rr){
          int op = op_lds[r4e + rr];
          f32x4 e4 = *(const f32x4*)&Ep2_l[op*G4 + je*4];
          z0[rr] += e4.x; z1[rr] += e4.y; z2[rr] += e4.z; z3[rr] += e4.w;
        }
      }
      const int grp  = ((je>>3) + rg) & 15;              // matches G's swizzle
      const int base = grp*8 + (je&7);
      #pragma unroll
      for (int rr = 0; rr < 4; ++rr){
        float cn_ = sigf(z1[rr])*c_st[rr] + sigf(z0[rr])*tanh_f(z2[rr]);
        c_st[rr] = cn_;
        float hv = sigf(z3[rr])*tanh_f(cn_);
        unsigned short hi = bf16hi(hv);
        unsigned short lo = bf16hi(hv - bf16f(hi));
        h_hi[(r4e+rr)*AST + base] = hi;
        h_lo[(r4e+rr)*AST + base] = lo;
      }
    } else {
      // lanes 800..831 (wave 12): gumbel noise for THIS step's sampling (read at G_{t+1})
      int r = tid - 800;
      const float* up = u + ((size_t)t*BTOT + row0 + r)*5;
      #pragma unroll
      for (int o = 0; o < 5; ++o){
        float uu = up[o];
        gn_lds[r*5 + o] = -__logf(-__logf(uu + EPSF) + EPSF);
      }
    }
    __syncthreads();   // b2: h_{t+1} frags + gn ready
  }

  if (tid >= 768 && tid < 800){
    int r = tid - 768;
    out[row0 + r]        = lp_acc;
    out[BTOT + row0 + r] = ent_acc;
  }
}

extern "C" void kernel_launch(void* const* d_in, const int* in_sizes, int n_in,
                              void* d_out, int out_size, void* d_ws, size_t ws_size,
                              hipStream_t stream) {
  const float* x0   = (const float*)d_in[0];
  const float* Wx   = (const float*)d_in[1];
  const float* Wh   = (const float*)d_in[2];
  const float* Wops = (const float*)d_in[3];
  const float* emb  = (const float*)d_in[4];
  const float* u    = (const float*)d_in[5];
  (void)d_ws; (void)ws_size; (void)in_sizes; (void)n_in;

  setup_bpack<<<(NTILE*KT8*64 + 255)/256, 256, 0, stream>>>(Wh, Wops);
  setup_emb<<<(6*G4 + 255)/256, 256, 0, stream>>>(emb, Wx);
  setup_z0<<<BTOT/64, 256, 0, stream>>>(x0, Wx);
  rnn_main<<<NBLK, BLOCK, 0, stream>>>(u, (float*)d_out);
}

// Round 7
// 2272.634 us; speedup vs baseline: 1.1708x; 1.1708x over previous
//
#include <hip/hip_runtime.h>
#include <cstdint>
#include <cstddef>

typedef __attribute__((ext_vector_type(8))) short short8;   // 8 bf16 (4 VGPRs)
typedef __attribute__((ext_vector_type(4))) short bfx4;     // 4 bf16 (8 B)
typedef __attribute__((ext_vector_type(4))) float f32x4;

#define HH     100
#define G4     400
#define NCOL   416          // 400 gates + 5 logits + 11 pad = 26 tiles of 16
#define NTIL   26
#define KTN    3            // 3 k-tiles of 32 -> k<96 via MFMA
#define KRES   96           // k=96..99 residual in f32
#define BTOT   8192
#define TST    512
#define ROWS   32
#define NBLK   256
#define BLOCK  832          // 13 waves; wave w owns tiles 2w, 2w+1
#define ZW     420          // z_lds row stride (words); 420/4=105 odd -> balanced
#define TANHC  1.5f
#define EPSF   1e-9f

__device__ unsigned short d_Bhi[NTIL*KTN*64*8];  // [W_h|W_ops|0] hi, B-frag order
__device__ unsigned short d_Blo[NTIL*KTN*64*8];  // lo residual
__device__ float d_Ep2[6*G4];                    // emb @ W_x   [e][je][g]
__device__ float d_WresG[NCOL*4];                // rows 96..99 of [W_h|W_ops|0], [n][q]
__device__ float d_Z0[(size_t)BTOT*G4];          // x0 @ W_x    [b][n]

static __device__ __forceinline__ unsigned short bf16hi(float f){
  unsigned u = __float_as_uint(f);
  return (unsigned short)((u + 0x7FFFu + ((u>>16)&1u)) >> 16);   // RNE
}
static __device__ __forceinline__ float bf16f(unsigned short s){
  return __uint_as_float(((unsigned)s)<<16);
}
static __device__ __forceinline__ float frcp(float x){ return __builtin_amdgcn_rcpf(x); }
static __device__ __forceinline__ float sigf(float x){ return frcp(1.0f + __expf(-x)); }
static __device__ __forceinline__ float tanh_f(float x){ return 1.0f - 2.0f*frcp(__expf(2.0f*x) + 1.0f); }

// ---- setup kernels -------------------------------------------------------

// B-frag order for 16x16x32: n = tile*16 + (lane&15), k = kt*32 + (lane>>4)*8 + i
__global__ void setup_bpack(const float* __restrict__ Wh, const float* __restrict__ Wops){
  int idx = blockIdx.x*blockDim.x + threadIdx.x;     // NTIL*KTN*64 = 4992
  if (idx >= NTIL*KTN*64) return;
  int tile = idx/(KTN*64), rem = idx - tile*(KTN*64), kt = rem>>6, ln = rem&63;
  int n = tile*16 + (ln & 15);
  #pragma unroll
  for (int i = 0; i < 8; ++i){
    int k = kt*32 + (ln>>4)*8 + i;                   // k < 96 always
    float w = 0.f;
    if (n < G4)          w = Wh[k*G4 + n];
    else if (n < G4+5)   w = Wops[k*5 + (n - G4)];
    unsigned short hi = bf16hi(w);
    unsigned short lo = bf16hi(w - bf16f(hi));
    d_Bhi[idx*8+i] = hi;
    d_Blo[idx*8+i] = lo;
  }
}

__global__ void setup_misc(const float* __restrict__ emb, const float* __restrict__ Wx,
                           const float* __restrict__ Wh, const float* __restrict__ Wops){
  int idx = blockIdx.x*blockDim.x + threadIdx.x;
  if (idx < 6*G4){                                   // Ep2 [e][je][g]
    int e = idx/G4, r2 = idx - e*G4, je = r2>>2, g = r2&3;
    float s = 0.f;
    for (int k = 0; k < HH; ++k) s = fmaf(emb[e*HH+k], Wx[k*G4 + g*HH + je], s);
    d_Ep2[idx] = s;
  } else if (idx < 6*G4 + NCOL*4){                   // residual rows 96..99
    int i = idx - 6*G4, n = i>>2, q = i&3;
    float w = 0.f;
    if (n < G4)        w = Wh[(KRES+q)*G4 + n];
    else if (n < G4+5) w = Wops[(KRES+q)*5 + (n - G4)];
    d_WresG[i] = w;
  }
}

// Z0 = x0 @ W_x, stored [b][n]
__global__ __launch_bounds__(256) void setup_z0(const float* __restrict__ x0,
                                                const float* __restrict__ Wx){
  __shared__ float xs[64*101];
  const int bb = blockIdx.x * 64;                    // 128 blocks
  for (int i = threadIdx.x; i < 64*HH; i += 256){
    int r = i/HH, k = i - r*HH;
    xs[r*101 + k] = x0[(size_t)(bb + r)*HH + k];
  }
  __syncthreads();
  const int bl = threadIdx.x & 63;
  for (int ng = threadIdx.x >> 6; ng < HH; ng += 4){
    f32x4 a = {0.f,0.f,0.f,0.f};
    for (int k = 0; k < HH; ++k){
      f32x4 w = *(const f32x4*)&Wx[k*G4 + ng*4];
      a += w * xs[bl*101 + k];
    }
    *(f32x4*)&d_Z0[(size_t)(bb + bl)*G4 + ng*4] = a;
  }
}

// ---- main persistent kernel ---------------------------------------------

__global__ __launch_bounds__(BLOCK) void rnn_main(
    const float* __restrict__ u, float* __restrict__ out)
{
  __shared__ __align__(16) float z_lds[ROWS*ZW];                // 53760 B [row][col]
  __shared__ __align__(16) unsigned short fhi[2*KTN*64*8];      //  6144 B A-frag order
  __shared__ __align__(16) unsigned short flo[2*KTN*64*8];      //  6144 B
  __shared__ __align__(16) float h_res[4*ROWS];                 //   512 B [q][r]
  __shared__ __align__(16) float Ep2_l[6*G4];                   //  9600 B
  __shared__ __align__(16) float Wres_l[NCOL*4];                //  6656 B
  __shared__ __align__(16) float samp[5*36];                    //   720 B
  __shared__ __align__(16) float gn_lds[ROWS*5];                //   640 B
  __shared__ int op_lds[ROWS];

  const int tid  = threadIdx.x;
  const int wave = tid >> 6;
  const int lane = tid & 63;
  const int cn   = lane & 15;       // col-in-tile (B,C) / row-in-tile (A)
  const int q4   = lane >> 4;       // quad
  const int row0 = blockIdx.x * ROWS;
  // E-phase mapping: jg = 4-cell group, r = row
  const int jg   = tid >> 5;        // 0..25 (only <25 used)
  const int rE   = tid & 31;

  for (int i = tid; i < 6*G4;   i += BLOCK) Ep2_l[i]  = d_Ep2[i];
  for (int i = tid; i < NCOL*4; i += BLOCK) Wres_l[i] = d_WresG[i];

  short8 bh[2][KTN], bl[2][KTN];
  {
    const short8* bph = (const short8*)d_Bhi;
    const short8* bpl = (const short8*)d_Blo;
    #pragma unroll
    for (int tl = 0; tl < 2; ++tl)
      #pragma unroll
      for (int kt = 0; kt < KTN; ++kt){
        int fi = ((wave*2 + tl)*KTN + kt)*64 + lane;
        bh[tl][kt] = bph[fi];
        bl[tl][kt] = bpl[fi];
      }
  }

  float c_st[4] = {0.f,0.f,0.f,0.f};
  float lp_acc = 0.f, ent_acc = 0.f;

  for (int t = 0; t <= TST; ++t){
    if (t == 0){
      // stage z_0 = x0 @ W_x (gates only)
      if (tid < 800){
        #pragma unroll
        for (int i = 0; i < 4; ++i){
          f32x4 v = *(const f32x4*)&d_Z0[(size_t)(row0 + rE)*G4 + jg*16 + i*4];
          *(f32x4*)&z_lds[rE*ZW + jg*16 + i*4] = v;
        }
      }
    } else {
      // ---- G: z_t = h_t @ [W_h|W_ops]  (MFMA k<96 + f32 residual) ----
      #pragma unroll
      for (int mt = 0; mt < 2; ++mt){
        short8 ah[KTN], al[KTN];
        #pragma unroll
        for (int kt = 0; kt < KTN; ++kt){
          ah[kt] = *(const short8*)&fhi[((mt*KTN + kt)*64 + lane)*8];
          al[kt] = *(const short8*)&flo[((mt*KTN + kt)*64 + lane)*8];
        }
        f32x4 hq[4];
        #pragma unroll
        for (int q = 0; q < 4; ++q)                       // broadcast reads
          hq[q] = *(const f32x4*)&h_res[q*ROWS + mt*16 + q4*4];
        #pragma unroll
        for (int tl = 0; tl < 2; ++tl){
          const int n = (wave*2 + tl)*16 + cn;
          f32x4 acc = {0.f,0.f,0.f,0.f};
          #pragma unroll
          for (int kt = 0; kt < KTN; ++kt){
            acc = __builtin_amdgcn_mfma_f32_16x16x32_bf16(ah[kt], bh[tl][kt], acc, 0,0,0);
            acc = __builtin_amdgcn_mfma_f32_16x16x32_bf16(al[kt], bh[tl][kt], acc, 0,0,0);
            acc = __builtin_amdgcn_mfma_f32_16x16x32_bf16(ah[kt], bl[tl][kt], acc, 0,0,0);
            acc = __builtin_amdgcn_mfma_f32_16x16x32_bf16(al[kt], bl[tl][kt], acc, 0,0,0);
          }
          f32x4 wr = *(const f32x4*)&Wres_l[n*4];
          #pragma unroll
          for (int q = 0; q < 4; ++q) acc += hq[q] * wr[q];
          const int rowb = mt*16 + q4*4;                  // C: row=q4*4+reg, col=cn
          #pragma unroll
          for (int i = 0; i < 4; ++i)
            z_lds[(rowb + i)*ZW + n] = acc[i];
          if (wave == 12 && tl == 1 && cn < 5)            // logits cols 400..404
            *(f32x4*)&samp[cn*36 + mt*16 + q4*4] = acc;
        }
      }
      // ---- sampling for step t-1 (wave 12; same-wave LDS dep) ----
      if (wave == 12 && lane < 32){
        int r = lane;
        float l[5];
        #pragma unroll
        for (int o = 0; o < 5; ++o) l[o] = TANHC * tanh_f(samp[o*36 + r]);
        int op = 0; float best = -1e30f;
        #pragma unroll
        for (int o = 0; o < 5; ++o){
          float v = l[o] + gn_lds[r*5 + o];
          if (v > best){ best = v; op = o; }              // strict >: first-max ties
        }
        float mx = fmaxf(fmaxf(fmaxf(l[0],l[1]), fmaxf(l[2],l[3])), l[4]);
        float se = 0.f;
        #pragma unroll
        for (int o = 0; o < 5; ++o) se += __expf(l[o] - mx);
        float lse = mx + __logf(se);
        float cur = lse - l[op];
        lp_acc  += cur;
        ent_acc += cur * __expf(-cur);
        op_lds[r] = op;
        out[2*BTOT + (size_t)(t-1)*BTOT + row0 + r] = (float)op;
      }
    }
    if (t == TST) break;
    __syncthreads();   // b1: z_t + op_{t-1} ready

    // ---- E: LSTM elementwise; thread = (jg: 4 cells, rE: 1 row) ----
    if (tid < 800){
      f32x4 zg[4];
      #pragma unroll
      for (int g = 0; g < 4; ++g)
        zg[g] = *(const f32x4*)&z_lds[rE*ZW + g*HH + jg*4];
      if (t > 0){
        const int op = op_lds[rE];
        #pragma unroll
        for (int i = 0; i < 4; ++i){
          f32x4 e4 = *(const f32x4*)&Ep2_l[op*G4 + (jg*4 + i)*4];
          zg[0][i] += e4.x; zg[1][i] += e4.y; zg[2][i] += e4.z; zg[3][i] += e4.w;
        }
      }
      float hv[4];
      #pragma unroll
      for (int i = 0; i < 4; ++i){
        float cn_ = sigf(zg[1][i])*c_st[i] + sigf(zg[0][i])*tanh_f(zg[2][i]);
        c_st[i] = cn_;
        hv[i] = sigf(zg[3][i])*tanh_f(cn_);
      }
      if (jg < 24){                                      // k = jg*4..+3 < 96 -> frags
        bfx4 h4, l4;
        #pragma unroll
        for (int i = 0; i < 4; ++i){
          unsigned short hi = bf16hi(hv[i]);
          h4[i] = (short)hi;
          l4[i] = (short)bf16hi(hv[i] - bf16f(hi));
        }
        const int kt   = jg >> 3;                        // k-tile
        const int lf   = (rE & 15) | (((jg >> 1) & 3) << 4);   // frag lane
        const int mt   = rE >> 4;
        const int j0   = (jg & 1) * 4;                   // halfword offset in lane
        const int base = ((mt*KTN + kt)*64 + lf)*8 + j0;
        *(bfx4*)&fhi[base] = h4;                         // single b64, 2-way banks
        *(bfx4*)&flo[base] = l4;
      } else {                                           // jg==24: k=96..99 residual
        #pragma unroll
        for (int i = 0; i < 4; ++i) h_res[i*ROWS + rE] = hv[i];
      }
    } else {
      // wave 12 lanes 32..63: gumbel noise for u[t] (consumed at G_{t+1})
      int r = tid - 800;
      const float* up = u + ((size_t)t*BTOT + row0 + r)*5;
      #pragma unroll
      for (int o = 0; o < 5; ++o){
        float uu = up[o];
        gn_lds[r*5 + o] = -__logf(-__logf(uu + EPSF) + EPSF);
      }
    }
    __syncthreads();   // b2: h_{t+1} frags + h_res + gn ready
  }

  if (wave == 12 && lane < 32){
    out[row0 + lane]        = lp_acc;
    out[BTOT + row0 + lane] = ent_acc;
  }
}

extern "C" void kernel_launch(void* const* d_in, const int* in_sizes, int n_in,
                              void* d_out, int out_size, void* d_ws, size_t ws_size,
                              hipStream_t stream) {
  const float* x0   = (const float*)d_in[0];
  const float* Wx   = (const float*)d_in[1];
  const float* Wh   = (const float*)d_in[2];
  const float* Wops = (const float*)d_in[3];
  const float* emb  = (const float*)d_in[4];
  const float* u    = (const float*)d_in[5];
  (void)d_ws; (void)ws_size; (void)in_sizes; (void)n_in;

  setup_bpack<<<(NTIL*KTN*64 + 255)/256, 256, 0, stream>>>(Wh, Wops);
  setup_misc<<<(6*G4 + NCOL*4 + 255)/256, 256, 0, stream>>>(emb, Wx, Wh, Wops);
  setup_z0<<<BTOT/64, 256, 0, stream>>>(x0, Wx);
  rnn_main<<<NBLK, BLOCK, 0, stream>>>(u, (float*)d_out);
}